// Round 1
// baseline (48.481 us; speedup 1.0000x reference)
//
#include <hip/hip_runtime.h>

#define NC      16
#define HW      (512 * 512)
#define NB      8
#define BPB     64                        // blocks per batch
#define THREADS 256
#define CHUNK   (HW / BPB)                // 4096 pixels per block
#define VITERS  (CHUNK / (THREADS * 4))   // 4 float4-iterations per thread

// bins layout in d_ws (floats): [0,128) inter[b][c], [128,256) denom[b][c],
// [256] ce_sum, [257] pen_sum
__global__ __launch_bounds__(THREADS) void domino_main(
    const float* __restrict__ logits,   // [B, C, H, W]
    const int*   __restrict__ tgt,      // [B, H, W]
    const float* __restrict__ penalty,  // [C, C] row = target class
    float*       __restrict__ bins)
{
    __shared__ float pen_t[NC * NC];    // transposed: pen_t[c*NC + t] = penalty[t*NC + c]
    __shared__ float red[4][34];

    const int tid = threadIdx.x;
    const int b   = blockIdx.x / BPB;
    const int blk = blockIdx.x % BPB;

    if (tid < NC * NC) {
        const int r = tid / NC, c = tid % NC;
        pen_t[c * NC + r] = penalty[tid];
    }
    __syncthreads();

    float inter_acc[NC], denom_acc[NC];
#pragma unroll
    for (int c = 0; c < NC; ++c) { inter_acc[c] = 0.f; denom_acc[c] = 0.f; }
    float ce_acc = 0.f, pen_acc = 0.f;

    const float* ob = logits + (size_t)b * NC * HW;
    const int*   tb = tgt    + (size_t)b * HW;

    for (int k = 0; k < VITERS; ++k) {
        const int g   = blk * (CHUNK / 4) + k * THREADS + tid;  // float4 group index
        const int pix = g * 4;

        float4 x[NC];
#pragma unroll
        for (int c = 0; c < NC; ++c)
            x[c] = *(const float4*)(ob + (size_t)c * HW + pix);
        const int4 t4 = *(const int4*)(tb + pix);

        // Process one pixel (component F of the float4 group), target TT.
        // All class-indexed arrays use compile-time indices only (no scratch).
#define PROC(F, TT) do {                                                    \
        const int t = (TT);                                                 \
        float m = -3.402823466e+38f;                                        \
        _Pragma("unroll")                                                   \
        for (int c = 0; c < NC; ++c) m = fmaxf(m, x[c].F);                  \
        float e[NC]; float s = 0.f, xt = 0.f;                               \
        _Pragma("unroll")                                                   \
        for (int c = 0; c < NC; ++c) {                                      \
            const float ee = __expf(x[c].F - m);                            \
            e[c] = ee; s += ee;                                             \
            xt += (t == c) ? x[c].F : 0.f;                                  \
        }                                                                   \
        const float inv = 1.0f / s;                                         \
        ce_acc += (__logf(s) + m) - xt;                                     \
        float pdot = 0.f;                                                   \
        _Pragma("unroll")                                                   \
        for (int c = 0; c < NC; ++c) {                                      \
            const float p = e[c] * inv;                                     \
            denom_acc[c] += p + ((t == c) ? 1.f : 0.f);                     \
            inter_acc[c] += (t == c) ? p : 0.f;                             \
            pdot += pen_t[c * NC + t] * p;                                  \
        }                                                                   \
        pen_acc += pdot;                                                    \
    } while (0)

        PROC(x, t4.x);
        PROC(y, t4.y);
        PROC(z, t4.z);
        PROC(w, t4.w);
#undef PROC
    }

    // Intra-wave butterfly reductions (64 lanes).
#pragma unroll
    for (int c = 0; c < NC; ++c) {
#pragma unroll
        for (int off = 32; off; off >>= 1) {
            inter_acc[c] += __shfl_xor(inter_acc[c], off);
            denom_acc[c] += __shfl_xor(denom_acc[c], off);
        }
    }
#pragma unroll
    for (int off = 32; off; off >>= 1) {
        ce_acc  += __shfl_xor(ce_acc,  off);
        pen_acc += __shfl_xor(pen_acc, off);
    }

    const int lane = tid & 63, wid = tid >> 6;
    if (lane == 0) {
#pragma unroll
        for (int c = 0; c < NC; ++c) {
            red[wid][c]      = inter_acc[c];
            red[wid][NC + c] = denom_acc[c];
        }
        red[wid][32] = ce_acc;
        red[wid][33] = pen_acc;
    }
    __syncthreads();

    if (tid < 34) {
        const float v = red[0][tid] + red[1][tid] + red[2][tid] + red[3][tid];
        float* dst;
        if (tid < 16)       dst = &bins[b * NC + tid];
        else if (tid < 32)  dst = &bins[NB * NC + b * NC + (tid - 16)];
        else if (tid == 32) dst = &bins[2 * NB * NC];
        else                dst = &bins[2 * NB * NC + 1];
        atomicAdd(dst, v);
    }
}

__global__ void domino_final(const float* __restrict__ bins, float* __restrict__ out)
{
    const int tid = threadIdx.x;  // 128 threads, one per (b,c) bin
    const float inter = bins[tid];
    const float denom = bins[128 + tid];
    float d = 1.0f - (2.0f * inter + 1e-5f) / (denom + 1e-5f);
#pragma unroll
    for (int off = 32; off; off >>= 1) d += __shfl_xor(d, off);
    __shared__ float w2[2];
    if ((tid & 63) == 0) w2[tid >> 6] = d;
    __syncthreads();
    if (tid == 0) {
        const float dice = (w2[0] + w2[1]) * (1.0f / 128.0f);
        const float ce   = bins[256] * (1.0f / (8.0f * 262144.0f));
        const float pen  = bins[257] * (1.0f / 8.0f);
        out[0] = ce + dice + pen;
    }
}

extern "C" void kernel_launch(void* const* d_in, const int* in_sizes, int n_in,
                              void* d_out, int out_size, void* d_ws, size_t ws_size,
                              hipStream_t stream)
{
    const float* logits = (const float*)d_in[0];   // [8,16,512,512] f32
    const int*   tgt    = (const int*)d_in[1];     // [8,1,512,512] int32
    const float* pen    = (const float*)d_in[2];   // [16,16] f32
    float*       bins   = (float*)d_ws;
    float*       out    = (float*)d_out;

    hipMemsetAsync(bins, 0, 258 * sizeof(float), stream);
    domino_main<<<NB * BPB, THREADS, 0, stream>>>(logits, tgt, pen, bins);
    domino_final<<<1, 128, 0, stream>>>(bins, out);
}